// Round 7
// baseline (675.140 us; speedup 1.0000x reference)
//
#include <hip/hip_runtime.h>
#include <stdint.h>

#define BB 8
#define LL 2048
#define DD 1024
#define HH 1024
#define BL (BB*LL)   // 16384

typedef __attribute__((ext_vector_type(8))) short short8;
typedef __attribute__((ext_vector_type(4))) float f32x4;

__device__ __forceinline__ unsigned short f2bf(float f) {
  unsigned int x = __float_as_uint(f);
  unsigned int r = (x + 0x7fffu + ((x >> 16) & 1u)) >> 16;
  return (unsigned short)r;
}
__device__ __forceinline__ float bf2f(unsigned short u) {
  return __uint_as_float(((unsigned int)u) << 16);
}

__device__ __forceinline__ void stage16(const unsigned short* g, unsigned short* l) {
  __builtin_amdgcn_global_load_lds((const __attribute__((address_space(1))) void*)g,
                                   (__attribute__((address_space(3))) void*)l,
                                   16, 0, 0);
}

// ================= v7 core: v5 ledger + lgkm ladder =================
// 512 threads = 8 waves (2M x 4N). MI=8: BM=256 (LDS 128K); MI=4: BM=128 (96K).
// BN=256, BK=64, 2 LDS buffers. Per K-tile: 24 (MI8) / 16 (MI4) ds_read_b128
// per wave (minimal), 2 s_barriers, ONE counted vmcnt (T4: never 0 mid-loop).
//
// MI=8 ladder (per wave; lgkm counts ds_read only -- global_load_lds is vmcnt):
//   SA(t+1)x4vm ; LDBk0(4) afk0(4) af1k0(4) [12]
//   lgkm(4)  -> MM(af0,k0)   (oldest 8 = LDBk0+af0k0 done)
//   LDBk1(4) af0k1(4) [12]
//   lgkm(8)  -> MM(af1,k0)   (af1k0 done)
//   af1k1(4) [12]
//   lgkm(4)  -> MM(af0,k1)   (LDBk1+af0k1 done)
//   BARRIER  (every wave passed lgkm(4) => all B(t) reads complete)
//   SB(t+2)x4vm  (overwrites p.b safely)
//   lgkm(0)  -> MM(af1,k1)
//   vmcnt(4) (drains SB(t+1)leftover + SA(t+1) = tile t+1; leaves SB(t+2))
//   BARRIER
// vm ledger MI8: prologue {A0,B0}=8 +{B1}=4 -> vmcnt(4) drains tile0. Steady:
// [SB(t+1):4][SA(t+1):4][SB(t+2):4] -> vmcnt(4) drains tile t+1 exactly.
// Tails: s1-only -> vmcnt(0) (8 out); last tile -> nothing outstanding.
// MI=4: SA=2 inst, SB=4; prologue 6+4 -> vmcnt(4) drains 6 = tile0; steady
// [4][2][4]=10 -> vmcnt(4) drains 6 = tile t+1. Same constants.
// Every inline-asm waitcnt is followed by sched_barrier(0) (rule 18); asm
// "memory" clobbers fence the read groups so the ladder counts are exact.
template<int MI>
struct __align__(16) SmemT {
  unsigned short a[2][MI*2048];   // BM x 64 per buffer
  unsigned short b[2][16384];     // 256 x 64 per buffer
};

template<int MI>
__device__ __forceinline__ void acc_initT(f32x4 (&acc)[MI][4]) {
#pragma unroll
  for (int i = 0; i < MI; ++i)
#pragma unroll
    for (int j = 0; j < 4; ++j)
      acc[i][j] = (f32x4){0.f, 0.f, 0.f, 0.f};
}

#define SCB __builtin_amdgcn_sched_barrier(0)

template<int MI, class FA, class FB>
__device__ __forceinline__ void gemm9_core(FA srcA, FB srcB, int NK,
                                           SmemT<MI>* sm, f32x4 (&acc)[MI][4]) {
  const int lane = threadIdx.x & 63;
  const int wave = threadIdx.x >> 6;           // 0..7
  const int srow = lane >> 3;                  // 0..7
  const int scol = ((lane & 7) ^ srow) * 8;    // swizzled source column
  const int fk = (lane >> 4) * 8;
  const int fr = lane & 15;
  const int fx = fr & 7;
  const int mwr = (wave >> 2) * (MI * 16);     // wave row base
  const int nwr = (wave & 3) * 64;             // wave col base
  const int cA0 = (MI == 8) ? ((wave < 4) ? 2 * wave : 2 * wave + 8) : 2 * wave;
  const int cA1 = cA0 + 8;                     // MI=8 only
  const int cB0 = (wave >> 1) * 8 + 2 * (wave & 1);
  const int cB1 = cB0 + 4;
  const int kc0 = (((fk >> 3) ^ fx) << 3);
  const int kc1 = ((((32 + fk) >> 3) ^ fx) << 3);

  auto SA2 = [&](int p, int kt, int c) {
    stage16(srcA(c * 8 + srow, kt) + scol, &sm->a[p][c * 512]);
    stage16(srcA(c * 8 + 8 + srow, kt) + scol, &sm->a[p][(c + 1) * 512]);
  };
  auto SB2 = [&](int p, int kt, int c) {
    stage16(srcB(c * 8 + srow, kt) + scol, &sm->b[p][c * 512]);
    stage16(srcB(c * 8 + 8 + srow, kt) + scol, &sm->b[p][(c + 1) * 512]);
  };

  short8 af0[4], af1[4], bfv[4][2];
  auto LDB4 = [&](int p, int kk, int kc) {
#pragma unroll
    for (int j = 0; j < 4; ++j)
      bfv[j][kk] = *(const short8*)&sm->b[p][(nwr + j * 16 + fr) * 64 + kc];
  };
  auto LDA4 = [&](short8 (&dst)[4], int p, int iho, int kc) {
#pragma unroll
    for (int i = 0; i < 4; ++i)
      dst[i] = *(const short8*)&sm->a[p][(mwr + iho + i * 16 + fr) * 64 + kc];
  };
  auto MM16 = [&](short8 (&a4)[4], int accb, int kk) {
#pragma unroll
    for (int i = 0; i < 4; ++i)
#pragma unroll
      for (int j = 0; j < 4; ++j)
        acc[accb + i][j] = __builtin_amdgcn_mfma_f32_16x16x32_bf16(
            a4[i], bfv[j][kk], acc[accb + i][j], 0, 0, 0);
  };

  // prologue: tile 0 + B(1)
  SA2(0, 0, cA0);
  if (MI == 8) SA2(0, 0, cA1);
  SB2(0, 0, cB0); SB2(0, 0, cB1);
  if (NK > 1) {
    SB2(1, 1, cB0); SB2(1, 1, cB1);
    asm volatile("s_waitcnt vmcnt(4)" ::: "memory");
  } else {
    asm volatile("s_waitcnt vmcnt(0)" ::: "memory");
  }
  SCB; __builtin_amdgcn_s_barrier(); SCB;

  for (int t = 0; t < NK; ++t) {
    const int p = t & 1, po = p ^ 1;
    const bool s1 = (t + 1 < NK), s2 = (t + 2 < NK);
    if (s1) { SA2(po, t + 1, cA0); if (MI == 8) SA2(po, t + 1, cA1); }
    if constexpr (MI == 8) {
      LDB4(p, 0, kc0);
      LDA4(af0, p, 0, kc0);
      LDA4(af1, p, 64, kc0);
      asm volatile("s_waitcnt lgkmcnt(4)" ::: "memory"); SCB;
      __builtin_amdgcn_s_setprio(1); MM16(af0, 0, 0); __builtin_amdgcn_s_setprio(0);
      LDB4(p, 1, kc1);
      LDA4(af0, p, 0, kc1);
      asm volatile("s_waitcnt lgkmcnt(8)" ::: "memory"); SCB;
      __builtin_amdgcn_s_setprio(1); MM16(af1, 4, 0); __builtin_amdgcn_s_setprio(0);
      LDA4(af1, p, 64, kc1);
      asm volatile("s_waitcnt lgkmcnt(4)" ::: "memory"); SCB;
      __builtin_amdgcn_s_setprio(1); MM16(af0, 0, 1); __builtin_amdgcn_s_setprio(0);
      SCB; __builtin_amdgcn_s_barrier(); SCB;
      if (s2) { SB2(p, t + 2, cB0); SB2(p, t + 2, cB1); }
      asm volatile("s_waitcnt lgkmcnt(0)" ::: "memory"); SCB;
      __builtin_amdgcn_s_setprio(1); MM16(af1, 4, 1); __builtin_amdgcn_s_setprio(0);
      SCB;
    } else {
      LDB4(p, 0, kc0);
      LDA4(af0, p, 0, kc0);
      LDB4(p, 1, kc1);
      LDA4(af1, p, 0, kc1);
      asm volatile("s_waitcnt lgkmcnt(8)" ::: "memory"); SCB;
      __builtin_amdgcn_s_setprio(1); MM16(af0, 0, 0); __builtin_amdgcn_s_setprio(0);
      asm volatile("s_waitcnt lgkmcnt(0)" ::: "memory"); SCB;
      SCB; __builtin_amdgcn_s_barrier(); SCB;
      if (s2) { SB2(p, t + 2, cB0); SB2(p, t + 2, cB1); }
      __builtin_amdgcn_s_setprio(1); MM16(af1, 0, 1); __builtin_amdgcn_s_setprio(0);
      SCB;
    }
    if (s2)      { asm volatile("s_waitcnt vmcnt(4)" ::: "memory"); }
    else if (s1) { asm volatile("s_waitcnt vmcnt(0)" ::: "memory"); }
    SCB; __builtin_amdgcn_s_barrier(); SCB;
  }
}

// per-element epilogue: body(rr, cc, av) within the (MI*32) x 256 tile
template<int MI, typename F>
__device__ __forceinline__ void epiT(const f32x4 (&acc)[MI][4], F body) {
  const int lane = threadIdx.x & 63;
  const int wave = threadIdx.x >> 6;
  const int mwr = (wave >> 2) * (MI * 16), nwr = (wave & 3) * 64;
#pragma unroll
  for (int i = 0; i < MI; ++i)
#pragma unroll
    for (int j = 0; j < 4; ++j)
#pragma unroll
      for (int jj = 0; jj < 4; ++jj)
        body(mwr + i * 16 + ((lane >> 4) << 2) + jj,
             nwr + j * 16 + (lane & 15), acc[i][j][jj]);
}

// ---------------- prep kernels ----------------

__global__ void k_zero(float4* __restrict__ p) {
  p[(size_t)blockIdx.x * 256 + threadIdx.x] = make_float4(0.f, 0.f, 0.f, 0.f);
}

__global__ void k_prep_x(const float* __restrict__ x, const float* __restrict__ wlr,
                         const float* __restrict__ wwd, unsigned short* __restrict__ xb,
                         float* __restrict__ lrlog, float* __restrict__ wdlog) {
  const int wave = threadIdx.x >> 6, lane = threadIdx.x & 63;
  const int row = blockIdx.x * 4 + wave;
  const float* xr = x + (size_t)row * DD;
  float s1 = 0.f, s2 = 0.f;
#pragma unroll
  for (int ch = 0; ch < 4; ++ch) {
    const int col = ch * 256 + lane * 4;
    float4 v = *(const float4*)(xr + col);
    float4 a = *(const float4*)(wlr + col);
    float4 b = *(const float4*)(wwd + col);
    s1 += v.x*a.x + v.y*a.y + v.z*a.z + v.w*a.w;
    s2 += v.x*b.x + v.y*b.y + v.z*b.z + v.w*b.w;
    uint2 u;
    u.x = (unsigned)f2bf(v.x) | ((unsigned)f2bf(v.y) << 16);
    u.y = (unsigned)f2bf(v.z) | ((unsigned)f2bf(v.w) << 16);
    *(uint2*)(xb + (size_t)row * DD + col) = u;
  }
#pragma unroll
  for (int off = 32; off > 0; off >>= 1) {
    s1 += __shfl_down(s1, off);
    s2 += __shfl_down(s2, off);
  }
  if (lane == 0) { lrlog[row] = s1; wdlog[row] = s2; }
}

__global__ void k_prep_w(const float* __restrict__ wq, const float* __restrict__ wk,
                         const float* __restrict__ wv, unsigned short* __restrict__ wqt,
                         unsigned short* __restrict__ wkt, unsigned short* __restrict__ wvtn,
                         unsigned short* __restrict__ wkr) {
  const int idx = blockIdx.x * 256 + threadIdx.x;
  if (blockIdx.z == 3) { wkr[idx] = f2bf(wk[idx]); return; }
  const int k = idx >> 10, n = idx & 1023;
  const float* src = (blockIdx.z == 0) ? wq : (blockIdx.z == 1) ? wk : wv;
  unsigned short* dst = (blockIdx.z == 0) ? wqt : (blockIdx.z == 1) ? wkt : wvtn;
  float v = src[(size_t)k * 1024 + n];
  if (blockIdx.z == 2) v = -v;
  dst[(size_t)n * 1024 + k] = f2bf(v);
}

__global__ void k_prep_h(const float* __restrict__ hid, unsigned short* __restrict__ wpb) {
  const size_t i = ((size_t)blockIdx.x * 256 + threadIdx.x) * 4;
  float4 v = *(const float4*)(hid + i);
  uint2 u;
  u.x = (unsigned)f2bf(v.x) | ((unsigned)f2bf(v.y) << 16);
  u.y = (unsigned)f2bf(v.z) | ((unsigned)f2bf(v.w) << 16);
  *(uint2*)(wpb + i) = u;
}

__global__ void k_bias2(const unsigned short* __restrict__ wpb, const float* __restrict__ bk,
                        const float* __restrict__ bv, float* __restrict__ bias2) {
  const int wave = threadIdx.x >> 6, lane = threadIdx.x & 63;
  const int row = blockIdx.x * 4 + wave;
  const unsigned short* wr = wpb + (size_t)row * HH;
  float s = 0.f;
#pragma unroll
  for (int ch = 0; ch < 4; ++ch) {
    const int col = ch * 256 + lane * 4;
    float4 a = *(const float4*)(bk + col);
    ushort4 u = *(const ushort4*)(wr + col);
    s += a.x * bf2f(u.x) + a.y * bf2f(u.y) + a.z * bf2f(u.z) + a.w * bf2f(u.w);
  }
#pragma unroll
  for (int off = 32; off > 0; off >>= 1) s += __shfl_down(s, off);
  if (lane == 0) bias2[row] = s - bv[row & 1023];
}

__global__ void k_scan(const float* __restrict__ lrlog, const float* __restrict__ wdlog,
                       const float* __restrict__ lbl, const float* __restrict__ blr,
                       const float* __restrict__ lbw, const float* __restrict__ bwd,
                       float* __restrict__ lr, float* __restrict__ c,
                       float* __restrict__ s, float* __restrict__ ecl) {
  const int b = blockIdx.x, t = threadIdx.x;
  __shared__ float sums[256];
  const float elr = expf(lbl[0]);
  const float ewd = expf(lbw[0]);
  const float blr0 = blr[0], bwd0 = bwd[0];
  float lw[8];
  const float* wb = wdlog + (size_t)b * LL + t * 8;
  float tot = 0.f;
#pragma unroll
  for (int i = 0; i < 8; ++i) {
    float z = wb[i] + bwd0;
    float sig = 1.f / (1.f + expf(-z));
    tot += log1pf(-ewd * sig);
    lw[i] = tot;
  }
  sums[t] = tot;
  __syncthreads();
  for (int off = 1; off < 256; off <<= 1) {
    float v = (t >= off) ? sums[t - off] : 0.f;
    __syncthreads();
    sums[t] += v;
    __syncthreads();
  }
  const float prev = (t > 0) ? sums[t - 1] : 0.f;
  const float ctot = sums[255];
  const float* lb = lrlog + (size_t)b * LL + t * 8;
#pragma unroll
  for (int i = 0; i < 8; ++i) {
    const int idx = b * LL + t * 8 + i;
    const float ci = prev + lw[i];
    c[idx] = ci;
    float zl = lb[i] + blr0;
    float lri = elr / (1.f + expf(-zl));
    lr[idx] = lri;
    s[idx] = lri * expf(ctot - ci);
  }
  if (t == 0) ecl[b] = expf(ctot);
}

// ---------------- GEMM kernels ----------------

// W2T[b][d][j] = sum_h Wp[b,d,h]*Wk[j,h] - Wv[j,d]  (MI=4, 128x256 tiles, 256 blocks)
__global__ __launch_bounds__(512, 2) void k9_gemm_m2(const unsigned short* __restrict__ wpb,
    const unsigned short* __restrict__ wkr, const unsigned short* __restrict__ wvtn,
    unsigned short* __restrict__ w2t) {
  __shared__ SmemT<4> sm;
  const int b = blockIdx.x;
  const int mt = blockIdx.y & 7, nt = blockIdx.y >> 3;
  const int m0 = mt * 128, n0 = nt * 256;
  f32x4 acc[4][4]; acc_initT<4>(acc);
  gemm9_core<4>(
    [&](int r, int kt) { return wpb + (size_t)b * DD * HH + (size_t)(m0 + r) * HH + kt * 64; },
    [&](int r, int kt) { return wkr + (size_t)(n0 + r) * HH + kt * 64; },
    HH / 64, &sm, acc);
  epiT<4>(acc, [&](int rr, int cc, float av) {
    const size_t gi = (size_t)(m0 + rr) * DD + (n0 + cc);
    w2t[(size_t)b * DD * DD + gi] = f2bf(av + bf2f(wvtn[gi]));   // wvtn = -Wv^T
  });
}

// Q = X*WqT + bq; q2 = exp(c[m]) * Q
__global__ __launch_bounds__(512, 2) void k9_gemm_q(const unsigned short* __restrict__ xb,
    const unsigned short* __restrict__ wt, const float* __restrict__ bias,
    const float* __restrict__ c, unsigned short* __restrict__ outb,
    unsigned short* __restrict__ q2b) {
  __shared__ SmemT<8> sm;
  const int mt = blockIdx.x * 8 + (blockIdx.y & 7);
  const int nt = blockIdx.y >> 3;
  const int m0 = mt * 256, n0 = nt * 256;
  f32x4 acc[8][4]; acc_initT<8>(acc);
  gemm9_core<8>(
    [&](int r, int kt) { return xb + (size_t)(m0 + r) * DD + kt * 64; },
    [&](int r, int kt) { return wt + (size_t)(n0 + r) * DD + kt * 64; },
    DD / 64, &sm, acc);
  const int lane = threadIdx.x & 63, wave = threadIdx.x >> 6;
  const int mwr = (wave >> 2) * 128, nwr = (wave & 3) * 64;
  float er[8][4];
#pragma unroll
  for (int i = 0; i < 8; ++i)
#pragma unroll
    for (int jj = 0; jj < 4; ++jj)
      er[i][jj] = __expf(c[m0 + mwr + i * 16 + ((lane >> 4) << 2) + jj]);
#pragma unroll
  for (int i = 0; i < 8; ++i)
#pragma unroll
    for (int j = 0; j < 4; ++j)
#pragma unroll
      for (int jj = 0; jj < 4; ++jj) {
        const int row = m0 + mwr + i * 16 + ((lane >> 4) << 2) + jj;
        const int col = n0 + nwr + j * 16 + (lane & 15);
        const float v = acc[i][j][jj] + bias[col];
        outb[(size_t)row * HH + col] = f2bf(v);
        q2b[(size_t)row * HH + col] = f2bf(v * er[i][jj]);
      }
}

__global__ __launch_bounds__(512, 2) void k9_gemm_k(const unsigned short* __restrict__ xb,
    const unsigned short* __restrict__ wt, const float* __restrict__ bias,
    const float* __restrict__ s, unsigned short* __restrict__ kb,
    unsigned short* __restrict__ k2t) {
  __shared__ SmemT<8> sm;
  const int mt = blockIdx.x * 8 + (blockIdx.y & 7);
  const int nt = blockIdx.y >> 3;
  const int m0 = mt * 256, n0 = nt * 256;
  f32x4 acc[8][4]; acc_initT<8>(acc);
  gemm9_core<8>(
    [&](int r, int kt) { return xb + (size_t)(m0 + r) * DD + kt * 64; },
    [&](int r, int kt) { return wt + (size_t)(n0 + r) * DD + kt * 64; },
    DD / 64, &sm, acc);
  const int lane = threadIdx.x & 63, wave = threadIdx.x >> 6;
  const int mwr = (wave >> 2) * 128, nwr = (wave & 3) * 64;
#pragma unroll
  for (int i = 0; i < 8; ++i)
#pragma unroll
    for (int j = 0; j < 4; ++j) {
      const int col = n0 + nwr + j * 16 + (lane & 15);
      const float bias_c = bias[col];
      const int row0 = m0 + mwr + i * 16 + ((lane >> 4) << 2);
      const int b = row0 >> 11, ml0 = row0 & 2047;
      unsigned short tmp[4];
#pragma unroll
      for (int jj = 0; jj < 4; ++jj) {
        float v = acc[i][j][jj] + bias_c;
        kb[(size_t)(row0 + jj) * HH + col] = f2bf(v);
        tmp[jj] = f2bf(v * s[row0 + jj]);
      }
      uint2 u;
      u.x = (unsigned)tmp[0] | ((unsigned)tmp[1] << 16);
      u.y = (unsigned)tmp[2] | ((unsigned)tmp[3] << 16);
      *(uint2*)&k2t[((size_t)b * HH + col) * LL + ml0] = u;
    }
}

// U = X*W2T + bias2, stored transposed ut[b][d][l]
__global__ __launch_bounds__(512, 2) void k9_gemm_u(const unsigned short* __restrict__ xb,
    const unsigned short* __restrict__ w2t, const float* __restrict__ bias2,
    unsigned short* __restrict__ ut) {
  __shared__ SmemT<8> sm;
  const int b = blockIdx.x;
  const int mt = blockIdx.x * 8 + (blockIdx.y & 7);
  const int nt = blockIdx.y >> 3;
  const int m0 = mt * 256, n0 = nt * 256;
  f32x4 acc[8][4]; acc_initT<8>(acc);
  gemm9_core<8>(
    [&](int r, int kt) { return xb + (size_t)(m0 + r) * DD + kt * 64; },
    [&](int r, int kt) { return w2t + (size_t)b * DD * DD + (size_t)(n0 + r) * DD + kt * 64; },
    DD / 64, &sm, acc);
  const int lane = threadIdx.x & 63, wave = threadIdx.x >> 6;
  const int mwr = (wave >> 2) * 128, nwr = (wave & 3) * 64;
#pragma unroll
  for (int i = 0; i < 8; ++i)
#pragma unroll
    for (int j = 0; j < 4; ++j) {
      const int col = n0 + nwr + j * 16 + (lane & 15);
      const float b2c = bias2[b * DD + col];
      const int row0 = m0 + mwr + i * 16 + ((lane >> 4) << 2);
      const int ml0 = row0 & 2047;
      unsigned short tmp[4];
#pragma unroll
      for (int jj = 0; jj < 4; ++jj) tmp[jj] = f2bf(acc[i][j][jj] + b2c);
      uint2 u;
      u.x = (unsigned)tmp[0] | ((unsigned)tmp[1] << 16);
      u.y = (unsigned)tmp[2] | ((unsigned)tmp[3] << 16);
      *(uint2*)&ut[((size_t)b * DD + col) * LL + ml0] = u;
    }
}

// pb[m,l] = -lr[l]*exp(c[m]-c[l]) * (Q K^T)[m,l] for l<=m, else 0.
__global__ __launch_bounds__(512, 2) void k9_gemm_p(const unsigned short* __restrict__ qb,
    const unsigned short* __restrict__ kb, const float* __restrict__ lr,
    const float* __restrict__ c, unsigned short* __restrict__ pb) {
  __shared__ SmemT<8> sm;
  const int b = blockIdx.x;                    // XCD = batch (L2 locality)
  const int t = blockIdx.y;                    // 0..35
  int mt = (int)((sqrtf(8.f * (float)t + 1.f) - 1.f) * 0.5f);
  while ((mt + 1) * (mt + 2) / 2 <= t) ++mt;
  while (mt * (mt + 1) / 2 > t) --mt;
  const int nt = t - mt * (mt + 1) / 2;
  const int base = b * LL;
  const int m0 = mt * 256, n0 = nt * 256;
  f32x4 acc[8][4]; acc_initT<8>(acc);
  gemm9_core<8>(
    [&](int rr, int kt) { return qb + (size_t)(base + m0 + rr) * HH + kt * 64; },
    [&](int rr, int kt) { return kb + (size_t)(base + n0 + rr) * HH + kt * 64; },
    HH / 64, &sm, acc);
  const int lane = threadIdx.x & 63, wave = threadIdx.x >> 6;
  const int mwr = (wave >> 2) * 128, nwr = (wave & 3) * 64;
  if (nt != mt) {
    const float cref = c[base + m0];
    float er[8][4], fc[4];
#pragma unroll
    for (int i = 0; i < 8; ++i)
#pragma unroll
      for (int jj = 0; jj < 4; ++jj)
        er[i][jj] = __expf(c[base + m0 + mwr + i * 16 + ((lane >> 4) << 2) + jj] - cref);
#pragma unroll
    for (int j = 0; j < 4; ++j) {
      const int l = n0 + nwr + j * 16 + (lane & 15);
      fc[j] = lr[base + l] * __expf(cref - c[base + l]);
    }
#pragma unroll
    for (int i = 0; i < 8; ++i)
#pragma unroll
      for (int j = 0; j < 4; ++j) {
        const int l = n0 + nwr + j * 16 + (lane & 15);
        const int row0 = m0 + mwr + i * 16 + ((lane >> 4) << 2);
#pragma unroll
        for (int jj = 0; jj < 4; ++jj) {
          const float v = -acc[i][j][jj] * er[i][jj] * fc[j];
          pb[((size_t)base + row0 + jj) * LL + l] = f2bf(v);
        }
      }
  } else {
    epiT<8>(acc, [&](int rr, int cc, float av) {
      const int m = m0 + rr, l = n0 + cc;
      float v = 0.f;
      if (l <= m) v = -av * lr[base + l] * __expf(c[base + m] - c[base + l]);
      pb[((size_t)base + m) * LL + l] = f2bf(v);
    });
  }
}

// y = pb*U + q2*Wp^T. Perfectly K-balanced: block (sr,nt) does half1 of tile
// mt=sr and half2 of tile mt=7-sr -> exactly 2(sr+1)+8 + 2(8-sr)+8 = 34
// K-tiles per block, all sr. Two contributors per output tile -> out is
// pre-zeroed (k_zero) and the epilogue uses f32 atomic adds (order-free).
// vmcnt(0) after each epilogue: atomics bump vmcnt, would corrupt the next
// core call's counted-vmcnt ledger otherwise.
__global__ __launch_bounds__(512, 2) void k9_gemm_y(const unsigned short* __restrict__ pb,
    const unsigned short* __restrict__ ut, const unsigned short* __restrict__ q2b,
    const unsigned short* __restrict__ wpb, float* __restrict__ out) {
  __shared__ SmemT<8> sm;
  const int b = blockIdx.x;
  const int sr = blockIdx.y & 7, nt = blockIdx.y >> 3;
  const int n0 = nt * 256;
  const unsigned short* pbB = pb + (size_t)b * LL * LL;
  const unsigned short* utB = ut + (size_t)b * DD * LL;
  const unsigned short* q2B = q2b + (size_t)b * LL * HH;
  const unsigned short* wpB = wpb + (size_t)b * DD * HH;
  f32x4 acc[8][4];
#pragma unroll
  for (int job = 0; job < 2; ++job) {
    const int mt = job ? (7 - sr) : sr;
    const int m0 = mt * 256;
    const int H = (mt + 1) * 2;             // half of the pb K-range
    const int pk0 = job ? H : 0;
    const int qk0 = job ? 8 : 0;
    acc_initT<8>(acc);
    gemm9_core<8>(
      [&](int r, int kt) { return pbB + (size_t)(m0 + r) * LL + (pk0 + kt) * 64; },
      [&](int r, int kt) { return utB + (size_t)(n0 + r) * LL + (pk0 + kt) * 64; },
      H, &sm, acc);
    gemm9_core<8>(
      [&](int r, int kt) { return q2B + (size_t)(m0 + r) * HH + (qk0 + kt) * 64; },
      [&](int r, int kt) { return wpB + (size_t)(n0 + r) * HH + (qk0 + kt) * 64; },
      8, &sm, acc);
    epiT<8>(acc, [&](int rr, int cc, float av) {
      unsafeAtomicAdd(&out[((size_t)b * LL + m0 + rr) * DD + (n0 + cc)], av);
    });
    asm volatile("s_waitcnt vmcnt(0)" ::: "memory");
    SCB;
  }
}

// W_next = -Ut * K2t^T + ecl[b]*W_prev  (MI=4, 128x256 tiles, 256 blocks)
__global__ __launch_bounds__(512, 2) void k9_gemm_wn(const unsigned short* __restrict__ ut,
    const unsigned short* __restrict__ k2t, const float* __restrict__ hid,
    const float* __restrict__ ecl, float* __restrict__ out2) {
  __shared__ SmemT<4> sm;
  const int b = blockIdx.x;
  const int mt = blockIdx.y & 7, nt = blockIdx.y >> 3;
  const int m0 = mt * 128, n0 = nt * 256;
  f32x4 acc[4][4]; acc_initT<4>(acc);
  gemm9_core<4>(
    [&](int r, int kt) { return ut + (size_t)b * DD * LL + (size_t)(m0 + r) * LL + kt * 64; },
    [&](int r, int kt) { return k2t + (size_t)b * HH * LL + (size_t)(n0 + r) * LL + kt * 64; },
    LL / 64, &sm, acc);
  const float eclb = ecl[b];
  epiT<4>(acc, [&](int rr, int cc, float av) {
    const size_t gi = ((size_t)b * DD + (m0 + rr)) * HH + (n0 + cc);
    out2[gi] = -av + eclb * hid[gi];
  });
}

// ---------------- launcher ----------------

extern "C" void kernel_launch(void* const* d_in, const int* in_sizes, int n_in,
                              void* d_out, int out_size, void* d_ws, size_t ws_size,
                              hipStream_t stream) {
  (void)in_sizes; (void)n_in; (void)out_size; (void)ws_size;
  const float* x   = (const float*)d_in[0];
  const float* hid = (const float*)d_in[1];
  const float* lbl = (const float*)d_in[2];
  const float* wlr = (const float*)d_in[3];
  const float* blr = (const float*)d_in[4];
  const float* lbw = (const float*)d_in[5];
  const float* wwd = (const float*)d_in[6];
  const float* bwd = (const float*)d_in[7];
  const float* wq  = (const float*)d_in[8];
  const float* bq  = (const float*)d_in[9];
  const float* wk  = (const float*)d_in[10];
  const float* bk  = (const float*)d_in[11];
  const float* wv  = (const float*)d_in[12];
  const float* bv  = (const float*)d_in[13];
  float* out = (float*)d_out;

  char* w = (char*)d_ws;
  constexpr size_t SZ_XB  = (size_t)BL * DD * 2;
  constexpr size_t SZ_QB  = (size_t)BL * HH * 2;
  constexpr size_t SZ_KB  = (size_t)BL * HH * 2;
  constexpr size_t SZ_K2T = (size_t)BB * HH * LL * 2;
  constexpr size_t SZ_UT  = (size_t)BB * DD * LL * 2;
  constexpr size_t SZ_PB  = (size_t)BB * LL * LL * 2;
  constexpr size_t SZ_WT  = (size_t)DD * HH * 2;
  constexpr size_t SZ_WPB = (size_t)BB * DD * HH * 2;
  constexpr size_t SZ_V16 = (size_t)BL * 4;

  size_t off = 0;
  unsigned short* xb   = (unsigned short*)(w + off); off += SZ_XB;
  unsigned short* qb   = (unsigned short*)(w + off); off += SZ_QB;
  unsigned short* kb   = (unsigned short*)(w + off); off += SZ_KB;
  unsigned short* k2t  = (unsigned short*)(w + off); off += SZ_K2T;
  unsigned short* ut   = (unsigned short*)(w + off); off += SZ_UT;
  unsigned short* pb   = (unsigned short*)(w + off); off += SZ_PB;
  unsigned short* wqt  = (unsigned short*)(w + off); off += SZ_WT;
  unsigned short* wkt  = (unsigned short*)(w + off); off += SZ_WT;
  unsigned short* wvtn = (unsigned short*)(w + off); off += SZ_WT;
  unsigned short* wpb  = (unsigned short*)(w + off); off += SZ_WPB;
  float* lrlog = (float*)(w + off); off += SZ_V16;
  float* wdlog = (float*)(w + off); off += SZ_V16;
  float* lr    = (float*)(w + off); off += SZ_V16;
  float* c     = (float*)(w + off); off += SZ_V16;
  float* s     = (float*)(w + off); off += SZ_V16;
  float* ecl   = (float*)(w + off); off += 256;
  float* bias2 = (float*)(w + off); off += (size_t)BB * DD * 4;

  // w2t (16.8 MB) + wkr (2 MB) alias the pb region: dead before k9_gemm_p writes pb.
  unsigned short* w2t = pb;
  unsigned short* wkr = pb + (size_t)BB * DD * DD;

  // q2 scratch lives in d_out's W_next region; overwritten by k9_gemm_wn afterwards.
  unsigned short* q2b = (unsigned short*)(out + (size_t)BL * DD);
  float* out2 = out + (size_t)BL * DD;

  k_zero<<<dim3(BL * DD / 4 / 256), 256, 0, stream>>>((float4*)out);
  k_prep_x<<<dim3(BL / 4), 256, 0, stream>>>(x, wlr, wwd, xb, lrlog, wdlog);
  k_prep_w<<<dim3(4096, 1, 4), 256, 0, stream>>>(wq, wk, wv, wqt, wkt, wvtn, wkr);
  k_prep_h<<<dim3((unsigned)((size_t)BB * DD * HH / 1024)), 256, 0, stream>>>(hid, wpb);
  k_scan<<<dim3(BB), 256, 0, stream>>>(lrlog, wdlog, lbl, blr, lbw, bwd, lr, c, s, ecl);
  k_bias2<<<dim3(BB * DD / 4), 256, 0, stream>>>(wpb, bk, bv, bias2);

  k9_gemm_m2<<<dim3(8, 32), 512, 0, stream>>>(wpb, wkr, wvtn, w2t);
  k9_gemm_q<<<dim3(8, 32), 512, 0, stream>>>(xb, wqt, bq, c, qb, q2b);
  k9_gemm_k<<<dim3(8, 32), 512, 0, stream>>>(xb, wkt, bk, s, kb, k2t);
  k9_gemm_u<<<dim3(8, 32), 512, 0, stream>>>(xb, w2t, bias2, ut);
  k9_gemm_p<<<dim3(8, 36), 512, 0, stream>>>(qb, kb, lr, c, pb);
  k9_gemm_y<<<dim3(8, 32), 512, 0, stream>>>(pb, ut, q2b, wpb, out);
  k9_gemm_wn<<<dim3(8, 32), 512, 0, stream>>>(ut, k2t, hid, ecl, out2);
}

// Round 8
// 581.216 us; speedup vs baseline: 1.1616x; 1.1616x over previous
//
#include <hip/hip_runtime.h>
#include <stdint.h>

#define BB 8
#define LL 2048
#define DD 1024
#define HH 1024
#define BL (BB*LL)   // 16384

typedef __attribute__((ext_vector_type(8))) short short8;
typedef __attribute__((ext_vector_type(4))) float f32x4;

__device__ __forceinline__ unsigned short f2bf(float f) {
  unsigned int x = __float_as_uint(f);
  unsigned int r = (x + 0x7fffu + ((x >> 16) & 1u)) >> 16;
  return (unsigned short)r;
}
__device__ __forceinline__ float bf2f(unsigned short u) {
  return __uint_as_float(((unsigned int)u) << 16);
}

__device__ __forceinline__ void stage16(const unsigned short* g, unsigned short* l) {
  __builtin_amdgcn_global_load_lds((const __attribute__((address_space(1))) void*)g,
                                   (__attribute__((address_space(3))) void*)l,
                                   16, 0, 0);
}

// ================= v8 core: r5's proven v5 ladder, MI templated =================
// 512 threads = 8 waves (2M x 4N). MI=8: BM=256, LDS 128K; MI=4: BM=128, 96K.
// BN=256, BK=64, 2 buffers. Per K-tile/wave: 24 (MI8) / 16 (MI4) ds_read_b128
// (minimal), 2 s_barriers, ONE counted vmcnt (T4: never 0 mid-loop).
// MI8 path is instruction-for-instruction the round-5 (610us, best) core.
//   PH1: [SA(t+1)->po ; LDB(p) 8rd ; LDA(ih0,k0) 4rd] lgkm0 MM ; LDA(ih0,k1)
//        lgkm0 MM ; barrier
//   PH2: [SB(t+2)->p ; LDA(ih1,k0)] lgkm0 MM ; LDA(ih1,k1) lgkm0 MM ;
//        vmcnt(4) ; barrier
// MI4 drops the ih1 half (acc[4][4], 2 MM clusters):
//   PH1: [SA ; LDB ; LDA(k0)] lgkm0 MM(k0) ; barrier
//   PH2: [SB ; LDA(k1)] lgkm0 MM(k1) ; vmcnt(4) ; barrier
// Hazards (both MI): SB(t+2) overwrites p.b AFTER the PH1 barrier; every
// wave's B-reads complete before its first lgkm0 => safe. SA(po) overwrites
// po.a whose last reads finished before iter t-1's final barrier => safe.
// vm ledger MI8 (4 SA + 4 SB per wave): prologue 8+4 -> vmcnt(4) drains tile0;
// steady [SB(t+1):4][SA(t+1):4][SB(t+2):4] -> vmcnt(4) drains tile t+1.
// vm ledger MI4 (2 SA + 4 SB): prologue 6+4 -> vmcnt(4) drains 6 = tile0;
// steady [4][2][4] -> vmcnt(4) drains 6 = tile t+1. Same constants.
// Tails: s1-only -> vmcnt(0); last tile -> nothing outstanding.
template<int MI>
struct __align__(16) SmemT {
  unsigned short a[2][MI*2048];   // BM x 64 per buffer
  unsigned short b[2][16384];     // 256 x 64 per buffer
};

template<int MI>
__device__ __forceinline__ void acc_initT(f32x4 (&acc)[MI][4]) {
#pragma unroll
  for (int i = 0; i < MI; ++i)
#pragma unroll
    for (int j = 0; j < 4; ++j)
      acc[i][j] = (f32x4){0.f, 0.f, 0.f, 0.f};
}

#define SCB __builtin_amdgcn_sched_barrier(0)
#define LGKM0 do { asm volatile("s_waitcnt lgkmcnt(0)" ::: "memory"); SCB; } while (0)

template<int MI, class FA, class FB>
__device__ __forceinline__ void gemm10_core(FA srcA, FB srcB, int NK,
                                            SmemT<MI>* sm, f32x4 (&acc)[MI][4]) {
  const int lane = threadIdx.x & 63;
  const int wave = threadIdx.x >> 6;           // 0..7
  const int srow = lane >> 3;                  // 0..7
  const int scol = ((lane & 7) ^ srow) * 8;    // swizzled source column
  const int fk = (lane >> 4) * 8;
  const int fr = lane & 15;
  const int fx = fr & 7;
  const int mwr = (wave >> 2) * (MI * 16);     // wave row base
  const int nwr = (wave & 3) * 64;             // wave col base
  const int cA0 = (MI == 8) ? ((wave < 4) ? 2 * wave : 2 * wave + 8) : 2 * wave;
  const int cA1 = cA0 + 8;                     // MI=8 only
  const int cB0 = (wave >> 1) * 8 + 2 * (wave & 1);
  const int cB1 = cB0 + 4;
  const int kc0 = (((fk >> 3) ^ fx) << 3);
  const int kc1 = ((((32 + fk) >> 3) ^ fx) << 3);

  auto SA2 = [&](int p, int kt, int c) {
    stage16(srcA(c * 8 + srow, kt) + scol, &sm->a[p][c * 512]);
    stage16(srcA(c * 8 + 8 + srow, kt) + scol, &sm->a[p][(c + 1) * 512]);
  };
  auto SB2 = [&](int p, int kt, int c) {
    stage16(srcB(c * 8 + srow, kt) + scol, &sm->b[p][c * 512]);
    stage16(srcB(c * 8 + 8 + srow, kt) + scol, &sm->b[p][(c + 1) * 512]);
  };

  short8 af[4], bfv[4][2];
  auto LDB = [&](int p) {
#pragma unroll
    for (int j = 0; j < 4; ++j) {
      bfv[j][0] = *(const short8*)&sm->b[p][(nwr + j * 16 + fr) * 64 + kc0];
      bfv[j][1] = *(const short8*)&sm->b[p][(nwr + j * 16 + fr) * 64 + kc1];
    }
  };
  auto LDA4 = [&](int p, int iho, int kc) {
#pragma unroll
    for (int i = 0; i < 4; ++i)
      af[i] = *(const short8*)&sm->a[p][(mwr + iho + i * 16 + fr) * 64 + kc];
  };
  auto MMk = [&](int accb, int kk) {
#pragma unroll
    for (int i = 0; i < 4; ++i)
#pragma unroll
      for (int j = 0; j < 4; ++j)
        acc[accb + i][j] = __builtin_amdgcn_mfma_f32_16x16x32_bf16(
            af[i], bfv[j][kk], acc[accb + i][j], 0, 0, 0);
  };

  // prologue: tile 0 (A+B -> buf0) + B(1) -> buf1
  SA2(0, 0, cA0);
  if constexpr (MI == 8) SA2(0, 0, cA1);
  SB2(0, 0, cB0); SB2(0, 0, cB1);
  if (NK > 1) {
    SB2(1, 1, cB0); SB2(1, 1, cB1);
    asm volatile("s_waitcnt vmcnt(4)" ::: "memory");
  } else {
    asm volatile("s_waitcnt vmcnt(0)" ::: "memory");
  }
  SCB; __builtin_amdgcn_s_barrier(); SCB;

  for (int t = 0; t < NK; ++t) {
    const int p = t & 1, po = p ^ 1;
    const bool s1 = (t + 1 < NK), s2 = (t + 2 < NK);
    // ---- PH1 ----
    if (s1) { SA2(po, t + 1, cA0); if constexpr (MI == 8) SA2(po, t + 1, cA1); }
    LDB(p);
    LDA4(p, 0, kc0);
    LGKM0;
    __builtin_amdgcn_s_setprio(1); MMk(0, 0); __builtin_amdgcn_s_setprio(0);
    if constexpr (MI == 8) {
      LDA4(p, 0, kc1);
      LGKM0;
      __builtin_amdgcn_s_setprio(1); MMk(0, 1); __builtin_amdgcn_s_setprio(0);
      SCB; __builtin_amdgcn_s_barrier(); SCB;
      // ---- PH2 ----
      if (s2) { SB2(p, t + 2, cB0); SB2(p, t + 2, cB1); }
      LDA4(p, 64, kc0);
      LGKM0;
      __builtin_amdgcn_s_setprio(1); MMk(4, 0); __builtin_amdgcn_s_setprio(0);
      LDA4(p, 64, kc1);
      LGKM0;
      __builtin_amdgcn_s_setprio(1); MMk(4, 1); __builtin_amdgcn_s_setprio(0);
    } else {
      SCB; __builtin_amdgcn_s_barrier(); SCB;
      // ---- PH2 ----
      if (s2) { SB2(p, t + 2, cB0); SB2(p, t + 2, cB1); }
      LDA4(p, 0, kc1);
      LGKM0;
      __builtin_amdgcn_s_setprio(1); MMk(0, 1); __builtin_amdgcn_s_setprio(0);
    }
    SCB;
    if (s2)      { asm volatile("s_waitcnt vmcnt(4)" ::: "memory"); }
    else if (s1) { asm volatile("s_waitcnt vmcnt(0)" ::: "memory"); }
    SCB; __builtin_amdgcn_s_barrier(); SCB;
  }
}

// per-element epilogue: body(rr, cc, av) within the (MI*32) x 256 tile
template<int MI, typename F>
__device__ __forceinline__ void epiT(const f32x4 (&acc)[MI][4], F body) {
  const int lane = threadIdx.x & 63;
  const int wave = threadIdx.x >> 6;
  const int mwr = (wave >> 2) * (MI * 16), nwr = (wave & 3) * 64;
#pragma unroll
  for (int i = 0; i < MI; ++i)
#pragma unroll
    for (int j = 0; j < 4; ++j)
#pragma unroll
      for (int jj = 0; jj < 4; ++jj)
        body(mwr + i * 16 + ((lane >> 4) << 2) + jj,
             nwr + j * 16 + (lane & 15), acc[i][j][jj]);
}

// ---------------- prep kernels ----------------

__global__ void k_prep_x(const float* __restrict__ x, const float* __restrict__ wlr,
                         const float* __restrict__ wwd, unsigned short* __restrict__ xb,
                         float* __restrict__ lrlog, float* __restrict__ wdlog) {
  const int wave = threadIdx.x >> 6, lane = threadIdx.x & 63;
  const int row = blockIdx.x * 4 + wave;
  const float* xr = x + (size_t)row * DD;
  float s1 = 0.f, s2 = 0.f;
#pragma unroll
  for (int ch = 0; ch < 4; ++ch) {
    const int col = ch * 256 + lane * 4;
    float4 v = *(const float4*)(xr + col);
    float4 a = *(const float4*)(wlr + col);
    float4 b = *(const float4*)(wwd + col);
    s1 += v.x*a.x + v.y*a.y + v.z*a.z + v.w*a.w;
    s2 += v.x*b.x + v.y*b.y + v.z*b.z + v.w*b.w;
    uint2 u;
    u.x = (unsigned)f2bf(v.x) | ((unsigned)f2bf(v.y) << 16);
    u.y = (unsigned)f2bf(v.z) | ((unsigned)f2bf(v.w) << 16);
    *(uint2*)(xb + (size_t)row * DD + col) = u;
  }
#pragma unroll
  for (int off = 32; off > 0; off >>= 1) {
    s1 += __shfl_down(s1, off);
    s2 += __shfl_down(s2, off);
  }
  if (lane == 0) { lrlog[row] = s1; wdlog[row] = s2; }
}

__global__ void k_prep_w(const float* __restrict__ wq, const float* __restrict__ wk,
                         const float* __restrict__ wv, unsigned short* __restrict__ wqt,
                         unsigned short* __restrict__ wkt, unsigned short* __restrict__ wvtn,
                         unsigned short* __restrict__ wkr) {
  const int idx = blockIdx.x * 256 + threadIdx.x;
  if (blockIdx.z == 3) { wkr[idx] = f2bf(wk[idx]); return; }
  const int k = idx >> 10, n = idx & 1023;
  const float* src = (blockIdx.z == 0) ? wq : (blockIdx.z == 1) ? wk : wv;
  unsigned short* dst = (blockIdx.z == 0) ? wqt : (blockIdx.z == 1) ? wkt : wvtn;
  float v = src[(size_t)k * 1024 + n];
  if (blockIdx.z == 2) v = -v;
  dst[(size_t)n * 1024 + k] = f2bf(v);
}

__global__ void k_prep_h(const float* __restrict__ hid, unsigned short* __restrict__ wpb) {
  const size_t i = ((size_t)blockIdx.x * 256 + threadIdx.x) * 4;
  float4 v = *(const float4*)(hid + i);
  uint2 u;
  u.x = (unsigned)f2bf(v.x) | ((unsigned)f2bf(v.y) << 16);
  u.y = (unsigned)f2bf(v.z) | ((unsigned)f2bf(v.w) << 16);
  *(uint2*)(wpb + i) = u;
}

__global__ void k_bias2(const unsigned short* __restrict__ wpb, const float* __restrict__ bk,
                        const float* __restrict__ bv, float* __restrict__ bias2) {
  const int wave = threadIdx.x >> 6, lane = threadIdx.x & 63;
  const int row = blockIdx.x * 4 + wave;
  const unsigned short* wr = wpb + (size_t)row * HH;
  float s = 0.f;
#pragma unroll
  for (int ch = 0; ch < 4; ++ch) {
    const int col = ch * 256 + lane * 4;
    float4 a = *(const float4*)(bk + col);
    ushort4 u = *(const ushort4*)(wr + col);
    s += a.x * bf2f(u.x) + a.y * bf2f(u.y) + a.z * bf2f(u.z) + a.w * bf2f(u.w);
  }
#pragma unroll
  for (int off = 32; off > 0; off >>= 1) s += __shfl_down(s, off);
  if (lane == 0) bias2[row] = s - bv[row & 1023];
}

__global__ void k_scan(const float* __restrict__ lrlog, const float* __restrict__ wdlog,
                       const float* __restrict__ lbl, const float* __restrict__ blr,
                       const float* __restrict__ lbw, const float* __restrict__ bwd,
                       float* __restrict__ lr, float* __restrict__ c,
                       float* __restrict__ s, float* __restrict__ ecl) {
  const int b = blockIdx.x, t = threadIdx.x;
  __shared__ float sums[256];
  const float elr = expf(lbl[0]);
  const float ewd = expf(lbw[0]);
  const float blr0 = blr[0], bwd0 = bwd[0];
  float lw[8];
  const float* wb = wdlog + (size_t)b * LL + t * 8;
  float tot = 0.f;
#pragma unroll
  for (int i = 0; i < 8; ++i) {
    float z = wb[i] + bwd0;
    float sig = 1.f / (1.f + expf(-z));
    tot += log1pf(-ewd * sig);
    lw[i] = tot;
  }
  sums[t] = tot;
  __syncthreads();
  for (int off = 1; off < 256; off <<= 1) {
    float v = (t >= off) ? sums[t - off] : 0.f;
    __syncthreads();
    sums[t] += v;
    __syncthreads();
  }
  const float prev = (t > 0) ? sums[t - 1] : 0.f;
  const float ctot = sums[255];
  const float* lb = lrlog + (size_t)b * LL + t * 8;
#pragma unroll
  for (int i = 0; i < 8; ++i) {
    const int idx = b * LL + t * 8 + i;
    const float ci = prev + lw[i];
    c[idx] = ci;
    float zl = lb[i] + blr0;
    float lri = elr / (1.f + expf(-zl));
    lr[idx] = lri;
    s[idx] = lri * expf(ctot - ci);
  }
  if (t == 0) ecl[b] = expf(ctot);
}

// ---------------- GEMM kernels ----------------

// W2T[b][d][j] = sum_h Wp[b,d,h]*Wk[j,h] - Wv[j,d]  (MI=4, 128x256, 256 blocks)
__global__ __launch_bounds__(512, 2) void k10_gemm_m2(const unsigned short* __restrict__ wpb,
    const unsigned short* __restrict__ wkr, const unsigned short* __restrict__ wvtn,
    unsigned short* __restrict__ w2t) {
  __shared__ SmemT<4> sm;
  const int b = blockIdx.x;
  const int mt = blockIdx.y & 7, nt = blockIdx.y >> 3;
  const int m0 = mt * 128, n0 = nt * 256;
  f32x4 acc[4][4]; acc_initT<4>(acc);
  gemm10_core<4>(
    [&](int r, int kt) { return wpb + (size_t)b * DD * HH + (size_t)(m0 + r) * HH + kt * 64; },
    [&](int r, int kt) { return wkr + (size_t)(n0 + r) * HH + kt * 64; },
    HH / 64, &sm, acc);
  epiT<4>(acc, [&](int rr, int cc, float av) {
    const size_t gi = (size_t)(m0 + rr) * DD + (n0 + cc);
    w2t[(size_t)b * DD * DD + gi] = f2bf(av + bf2f(wvtn[gi]));   // wvtn = -Wv^T
  });
}

// Q = X*WqT + bq; q2 = exp(c[m]) * Q   (MI=8, identical to round-5 best)
__global__ __launch_bounds__(512, 2) void k10_gemm_q(const unsigned short* __restrict__ xb,
    const unsigned short* __restrict__ wt, const float* __restrict__ bias,
    const float* __restrict__ c, unsigned short* __restrict__ outb,
    unsigned short* __restrict__ q2b) {
  __shared__ SmemT<8> sm;
  const int mt = blockIdx.x * 8 + (blockIdx.y & 7);
  const int nt = blockIdx.y >> 3;
  const int m0 = mt * 256, n0 = nt * 256;
  f32x4 acc[8][4]; acc_initT<8>(acc);
  gemm10_core<8>(
    [&](int r, int kt) { return xb + (size_t)(m0 + r) * DD + kt * 64; },
    [&](int r, int kt) { return wt + (size_t)(n0 + r) * DD + kt * 64; },
    DD / 64, &sm, acc);
  const int lane = threadIdx.x & 63, wave = threadIdx.x >> 6;
  const int mwr = (wave >> 2) * 128, nwr = (wave & 3) * 64;
  float er[8][4];
#pragma unroll
  for (int i = 0; i < 8; ++i)
#pragma unroll
    for (int jj = 0; jj < 4; ++jj)
      er[i][jj] = __expf(c[m0 + mwr + i * 16 + ((lane >> 4) << 2) + jj]);
#pragma unroll
  for (int i = 0; i < 8; ++i)
#pragma unroll
    for (int j = 0; j < 4; ++j)
#pragma unroll
      for (int jj = 0; jj < 4; ++jj) {
        const int row = m0 + mwr + i * 16 + ((lane >> 4) << 2) + jj;
        const int col = n0 + nwr + j * 16 + (lane & 15);
        const float v = acc[i][j][jj] + bias[col];
        outb[(size_t)row * HH + col] = f2bf(v);
        q2b[(size_t)row * HH + col] = f2bf(v * er[i][jj]);
      }
}

__global__ __launch_bounds__(512, 2) void k10_gemm_k(const unsigned short* __restrict__ xb,
    const unsigned short* __restrict__ wt, const float* __restrict__ bias,
    const float* __restrict__ s, unsigned short* __restrict__ kb,
    unsigned short* __restrict__ k2t) {
  __shared__ SmemT<8> sm;
  const int mt = blockIdx.x * 8 + (blockIdx.y & 7);
  const int nt = blockIdx.y >> 3;
  const int m0 = mt * 256, n0 = nt * 256;
  f32x4 acc[8][4]; acc_initT<8>(acc);
  gemm10_core<8>(
    [&](int r, int kt) { return xb + (size_t)(m0 + r) * DD + kt * 64; },
    [&](int r, int kt) { return wt + (size_t)(n0 + r) * DD + kt * 64; },
    DD / 64, &sm, acc);
  const int lane = threadIdx.x & 63, wave = threadIdx.x >> 6;
  const int mwr = (wave >> 2) * 128, nwr = (wave & 3) * 64;
#pragma unroll
  for (int i = 0; i < 8; ++i)
#pragma unroll
    for (int j = 0; j < 4; ++j) {
      const int col = n0 + nwr + j * 16 + (lane & 15);
      const float bias_c = bias[col];
      const int row0 = m0 + mwr + i * 16 + ((lane >> 4) << 2);
      const int b = row0 >> 11, ml0 = row0 & 2047;
      unsigned short tmp[4];
#pragma unroll
      for (int jj = 0; jj < 4; ++jj) {
        float v = acc[i][j][jj] + bias_c;
        kb[(size_t)(row0 + jj) * HH + col] = f2bf(v);
        tmp[jj] = f2bf(v * s[row0 + jj]);
      }
      uint2 u;
      u.x = (unsigned)tmp[0] | ((unsigned)tmp[1] << 16);
      u.y = (unsigned)tmp[2] | ((unsigned)tmp[3] << 16);
      *(uint2*)&k2t[((size_t)b * HH + col) * LL + ml0] = u;
    }
}

// U = X*W2T + bias2, stored transposed ut[b][d][l]  (MI=8, as round 5)
__global__ __launch_bounds__(512, 2) void k10_gemm_u(const unsigned short* __restrict__ xb,
    const unsigned short* __restrict__ w2t, const float* __restrict__ bias2,
    unsigned short* __restrict__ ut) {
  __shared__ SmemT<8> sm;
  const int b = blockIdx.x;
  const int mt = blockIdx.x * 8 + (blockIdx.y & 7);
  const int nt = blockIdx.y >> 3;
  const int m0 = mt * 256, n0 = nt * 256;
  f32x4 acc[8][4]; acc_initT<8>(acc);
  gemm10_core<8>(
    [&](int r, int kt) { return xb + (size_t)(m0 + r) * DD + kt * 64; },
    [&](int r, int kt) { return w2t + (size_t)b * DD * DD + (size_t)(n0 + r) * DD + kt * 64; },
    DD / 64, &sm, acc);
  const int lane = threadIdx.x & 63, wave = threadIdx.x >> 6;
  const int mwr = (wave >> 2) * 128, nwr = (wave & 3) * 64;
#pragma unroll
  for (int i = 0; i < 8; ++i)
#pragma unroll
    for (int j = 0; j < 4; ++j) {
      const int col = n0 + nwr + j * 16 + (lane & 15);
      const float b2c = bias2[b * DD + col];
      const int row0 = m0 + mwr + i * 16 + ((lane >> 4) << 2);
      const int ml0 = row0 & 2047;
      unsigned short tmp[4];
#pragma unroll
      for (int jj = 0; jj < 4; ++jj) tmp[jj] = f2bf(acc[i][j][jj] + b2c);
      uint2 u;
      u.x = (unsigned)tmp[0] | ((unsigned)tmp[1] << 16);
      u.y = (unsigned)tmp[2] | ((unsigned)tmp[3] << 16);
      *(uint2*)&ut[((size_t)b * DD + col) * LL + ml0] = u;
    }
}

// pb[m,l] = -lr[l]*exp(c[m]-c[l]) * (Q K^T)[m,l] for l<=m, else 0.
// MI=4: 128x256 triangular tiles, 72/batch (mapping proven in round 2/3).
// Coverage: row-block mt writes cols [0,(floor(mt/2)+1)*256) which equals
// y's read range exactly. Direct mask form: exp evaluated only when l<=m
// (arg <= 0, c monotone decreasing -> no overflow).
__global__ __launch_bounds__(512, 2) void k10_gemm_p(const unsigned short* __restrict__ qb,
    const unsigned short* __restrict__ kb, const float* __restrict__ lr,
    const float* __restrict__ c, unsigned short* __restrict__ pb) {
  __shared__ SmemT<4> sm;
  const int b = blockIdx.x;                    // XCD = batch (L2 locality)
  const int t = blockIdx.y;                    // 0..71
  int r = (int)((sqrtf(4.f * (float)t + 1.f) - 1.f) * 0.5f);
  while ((r + 1) * (r + 2) <= t) ++r;
  while (r * (r + 1) > t) --r;
  const int u = t - r * (r + 1);               // 0..2r+1
  const int mt = 2 * r + (u > r ? 1 : 0);
  const int nt2 = (u > r) ? (u - r - 1) : u;
  const int base = b * LL;
  const int m0 = mt * 128, n0 = nt2 * 256;
  f32x4 acc[4][4]; acc_initT<4>(acc);
  gemm10_core<4>(
    [&](int rr, int kt) { return qb + (size_t)(base + m0 + rr) * HH + kt * 64; },
    [&](int rr, int kt) { return kb + (size_t)(base + n0 + rr) * HH + kt * 64; },
    HH / 64, &sm, acc);
  epiT<4>(acc, [&](int rr, int cc, float av) {
    const int m = m0 + rr, l = n0 + cc;
    float v = 0.f;
    if (l <= m) v = -av * lr[base + l] * __expf(c[base + m] - c[base + l]);
    pb[((size_t)base + m) * LL + l] = f2bf(v);
  });
}

// y = pb*U + q2*Wp^T. MI=4, tile-paired balance WITHOUT atomics: block
// (sr,nt) computes tile mt=sr fully, then tile mt=15-sr fully. Work =
// [2(sr+1)+16] + [2(16-sr)+16] = 66 K-tiles for every block. Each output
// tile written by exactly one block -> plain stores. Grid (8,32)=256 blocks.
// Ledger across the job boundary: job-0 epilogue stores are OLDER vmcnt
// entries than job-1's prologue loads, so the prologue vmcnt(4) drains them
// first -- counted-wait semantics stay exact.
__global__ __launch_bounds__(512, 2) void k10_gemm_y(const unsigned short* __restrict__ pb,
    const unsigned short* __restrict__ ut, const unsigned short* __restrict__ q2b,
    const unsigned short* __restrict__ wpb, float* __restrict__ out) {
  __shared__ SmemT<4> sm;
  const int b = blockIdx.x;
  const int sr = blockIdx.y & 7, nt = blockIdx.y >> 3;
  const int n0 = nt * 256;
  const unsigned short* pbB = pb + (size_t)b * LL * LL;
  const unsigned short* utB = ut + (size_t)b * DD * LL;
  const unsigned short* q2B = q2b + (size_t)b * LL * HH;
  const unsigned short* wpB = wpb + (size_t)b * DD * HH;
  f32x4 acc[4][4];
#pragma unroll
  for (int job = 0; job < 2; ++job) {
    const int mt = job ? (15 - sr) : sr;
    const int m0 = mt * 128;
    const int NK1 = (mt + 1) * 2;             // pb cols l < (mt+1)*128
    acc_initT<4>(acc);
    gemm10_core<4>(
      [&](int r, int kt) {
        return (kt < NK1) ? pbB + (size_t)(m0 + r) * LL + kt * 64
                          : q2B + (size_t)(m0 + r) * HH + (kt - NK1) * 64;
      },
      [&](int r, int kt) {
        return (kt < NK1) ? utB + (size_t)(n0 + r) * LL + kt * 64
                          : wpB + (size_t)(n0 + r) * HH + (kt - NK1) * 64;
      },
      NK1 + 16, &sm, acc);
    epiT<4>(acc, [&](int rr, int cc, float av) {
      out[((size_t)b * LL + m0 + rr) * DD + (n0 + cc)] = av;
    });
  }
}

// W_next = -Ut * K2t^T + ecl[b]*W_prev  (MI=4, 128x256, 256 blocks)
__global__ __launch_bounds__(512, 2) void k10_gemm_wn(const unsigned short* __restrict__ ut,
    const unsigned short* __restrict__ k2t, const float* __restrict__ hid,
    const float* __restrict__ ecl, float* __restrict__ out2) {
  __shared__ SmemT<4> sm;
  const int b = blockIdx.x;
  const int mt = blockIdx.y & 7, nt = blockIdx.y >> 3;
  const int m0 = mt * 128, n0 = nt * 256;
  f32x4 acc[4][4]; acc_initT<4>(acc);
  gemm10_core<4>(
    [&](int r, int kt) { return ut + (size_t)b * DD * LL + (size_t)(m0 + r) * LL + kt * 64; },
    [&](int r, int kt) { return k2t + (size_t)b * HH * LL + (size_t)(n0 + r) * LL + kt * 64; },
    LL / 64, &sm, acc);
  const float eclb = ecl[b];
  epiT<4>(acc, [&](int rr, int cc, float av) {
    const size_t gi = ((size_t)b * DD + (m0 + rr)) * HH + (n0 + cc);
    out2[gi] = -av + eclb * hid[gi];
  });
}

// ---------------- launcher ----------------

extern "C" void kernel_launch(void* const* d_in, const int* in_sizes, int n_in,
                              void* d_out, int out_size, void* d_ws, size_t ws_size,
                              hipStream_t stream) {
  (void)in_sizes; (void)n_in; (void)out_size; (void)ws_size;
  const float* x   = (const float*)d_in[0];
  const float* hid = (const float*)d_in[1];
  const float* lbl = (const float*)d_in[2];
  const float* wlr = (const float*)d_in[3];
  const float* blr = (const float*)d_in[4];
  const float* lbw = (const float*)d_in[5];
  const float* wwd = (const float*)d_in[6];
  const float* bwd = (const float*)d_in[7];
  const float* wq  = (const float*)d_in[8];
  const float* bq  = (const float*)d_in[9];
  const float* wk  = (const float*)d_in[10];
  const float* bk  = (const float*)d_in[11];
  const float* wv  = (const float*)d_in[12];
  const float* bv  = (const float*)d_in[13];
  float* out = (float*)d_out;

  char* w = (char*)d_ws;
  constexpr size_t SZ_XB  = (size_t)BL * DD * 2;
  constexpr size_t SZ_QB  = (size_t)BL * HH * 2;
  constexpr size_t SZ_KB  = (size_t)BL * HH * 2;
  constexpr size_t SZ_K2T = (size_t)BB * HH * LL * 2;
  constexpr size_t SZ_UT  = (size_t)BB * DD * LL * 2;
  constexpr size_t SZ_PB  = (size_t)BB * LL * LL * 2;
  constexpr size_t SZ_WT  = (size_t)DD * HH * 2;
  constexpr size_t SZ_WPB = (size_t)BB * DD * HH * 2;
  constexpr size_t SZ_V16 = (size_t)BL * 4;

  size_t off = 0;
  unsigned short* xb   = (unsigned short*)(w + off); off += SZ_XB;
  unsigned short* qb   = (unsigned short*)(w + off); off += SZ_QB;
  unsigned short* kb   = (unsigned short*)(w + off); off += SZ_KB;
  unsigned short* k2t  = (unsigned short*)(w + off); off += SZ_K2T;
  unsigned short* ut   = (unsigned short*)(w + off); off += SZ_UT;
  unsigned short* pb   = (unsigned short*)(w + off); off += SZ_PB;
  unsigned short* wqt  = (unsigned short*)(w + off); off += SZ_WT;
  unsigned short* wkt  = (unsigned short*)(w + off); off += SZ_WT;
  unsigned short* wvtn = (unsigned short*)(w + off); off += SZ_WT;
  unsigned short* wpb  = (unsigned short*)(w + off); off += SZ_WPB;
  float* lrlog = (float*)(w + off); off += SZ_V16;
  float* wdlog = (float*)(w + off); off += SZ_V16;
  float* lr    = (float*)(w + off); off += SZ_V16;
  float* c     = (float*)(w + off); off += SZ_V16;
  float* s     = (float*)(w + off); off += SZ_V16;
  float* ecl   = (float*)(w + off); off += 256;
  float* bias2 = (float*)(w + off); off += (size_t)BB * DD * 4;

  // w2t (16.8 MB) + wkr (2 MB) alias the pb region: dead before k10_gemm_p writes pb.
  unsigned short* w2t = pb;
  unsigned short* wkr = pb + (size_t)BB * DD * DD;

  // q2 scratch lives in d_out's W_next region; overwritten by k10_gemm_wn afterwards.
  unsigned short* q2b = (unsigned short*)(out + (size_t)BL * DD);
  float* out2 = out + (size_t)BL * DD;

  k_prep_x<<<dim3(BL / 4), 256, 0, stream>>>(x, wlr, wwd, xb, lrlog, wdlog);
  k_prep_w<<<dim3(4096, 1, 4), 256, 0, stream>>>(wq, wk, wv, wqt, wkt, wvtn, wkr);
  k_prep_h<<<dim3((unsigned)((size_t)BB * DD * HH / 1024)), 256, 0, stream>>>(hid, wpb);
  k_scan<<<dim3(BB), 256, 0, stream>>>(lrlog, wdlog, lbl, blr, lbw, bwd, lr, c, s, ecl);
  k_bias2<<<dim3(BB * DD / 4), 256, 0, stream>>>(wpb, bk, bv, bias2);

  k10_gemm_m2<<<dim3(8, 32), 512, 0, stream>>>(wpb, wkr, wvtn, w2t);
  k10_gemm_q<<<dim3(8, 32), 512, 0, stream>>>(xb, wqt, bq, c, qb, q2b);
  k10_gemm_k<<<dim3(8, 32), 512, 0, stream>>>(xb, wkt, bk, s, kb, k2t);
  k10_gemm_u<<<dim3(8, 32), 512, 0, stream>>>(xb, w2t, bias2, ut);
  k10_gemm_p<<<dim3(8, 72), 512, 0, stream>>>(qb, kb, lr, c, pb);
  k10_gemm_y<<<dim3(8, 32), 512, 0, stream>>>(pb, ut, q2b, wpb, out);
  k10_gemm_wn<<<dim3(8, 32), 512, 0, stream>>>(ut, k2t, hid, ecl, out2);
}

// Round 9
// 580.640 us; speedup vs baseline: 1.1628x; 1.0010x over previous
//
#include <hip/hip_runtime.h>
#include <stdint.h>

#define BB 8
#define LL 2048
#define DD 1024
#define HH 1024
#define BL (BB*LL)   // 16384

typedef __attribute__((ext_vector_type(8))) short short8;
typedef __attribute__((ext_vector_type(4))) float f32x4;

__device__ __forceinline__ unsigned short f2bf(float f) {
  unsigned int x = __float_as_uint(f);
  unsigned int r = (x + 0x7fffu + ((x >> 16) & 1u)) >> 16;
  return (unsigned short)r;
}
__device__ __forceinline__ float bf2f(unsigned short u) {
  return __uint_as_float(((unsigned int)u) << 16);
}

__device__ __forceinline__ void stage16(const unsigned short* g, unsigned short* l) {
  __builtin_amdgcn_global_load_lds((const __attribute__((address_space(1))) void*)g,
                                   (__attribute__((address_space(3))) void*)l,
                                   16, 0, 0);
}

// ================= v9 core =================
// 512 threads = 8 waves (2M x 4N). BN=256, BK=64, 2 LDS buffers.
// MI=4 path: byte-identical to round-8 (proven 581us baseline).
// MI=8 path: NEW -- m201-faithful fine-phase + counted vmcnt (the one untried
// combination: v6 had fine phases with drain-0; v5/v8 had counted vmcnt with
// coarse phases). Per K-tile, FOUR phases, each:
//   { quadrant ds_reads ; one stage pair } barrier ; lgkm0 ; setprio(1) ;
//   16 MFMA ; setprio(0) ; barrier
// Quadrant order (ih0k0, ih0k1, ih1k0, ih1k1) => B(t) fully consumed after
// PH2's closing barrier, so B(t+2) stages into the LIVE buffer at PH3/PH4;
// A(t+1) stages into the dead buffer at PH1/PH2. ONE counted vmcnt(4) at PH4
// (T4: never 0 mid-loop).
// vm ledger MI8 (per wave; SA2/SB2 = 2 insts): prologue tile0(8)+B(1)(4) ->
// vmcnt(4) drains tile0, leaves B(1):4. Steady, end of tile t:
// [B(t+1):4 (staged t-1.PH3/4)][A(t+1):4 (t.PH1/2)][B(t+2):4 (t.PH3/4)]
// -> vmcnt(4) drains tile t+1 exactly, leaves B(t+2) flying.
// Tails: s2 false & s1 true -> vmcnt(0) (8 outstanding, all tile t+1);
// s1 false -> nothing outstanding, no wait.
// Region-overwrite audit: SA2(po)@PH1/2: po holds tile t-1, A last read
// t-1.PH4 (barrier precedes) ; B last read t-1.PH2. SB2(p)@PH3/4: p.B last
// read t.PH2 (closing barrier precedes PH3). B(t+2) in p.B is not read until
// tile t+2's PH1, after the vmcnt(4)@t+1.PH4 that drains it + barrier.
// vm ledger MI4 (2 SA + 4 SB): prologue 6+4 -> vmcnt(4) drains 6 = tile0;
// steady [4][2][4] -> vmcnt(4) drains 6 = tile t+1. Same constants.
template<int MI>
struct __align__(16) SmemT {
  unsigned short a[2][MI*2048];   // BM x 64 per buffer
  unsigned short b[2][16384];     // 256 x 64 per buffer
};

template<int MI>
__device__ __forceinline__ void acc_initT(f32x4 (&acc)[MI][4]) {
#pragma unroll
  for (int i = 0; i < MI; ++i)
#pragma unroll
    for (int j = 0; j < 4; ++j)
      acc[i][j] = (f32x4){0.f, 0.f, 0.f, 0.f};
}

#define SCB __builtin_amdgcn_sched_barrier(0)
#define LGKM0 do { asm volatile("s_waitcnt lgkmcnt(0)" ::: "memory"); SCB; } while (0)

template<int MI, class FA, class FB>
__device__ __forceinline__ void gemm11_core(FA srcA, FB srcB, int NK,
                                            SmemT<MI>* sm, f32x4 (&acc)[MI][4]) {
  const int lane = threadIdx.x & 63;
  const int wave = threadIdx.x >> 6;           // 0..7
  const int srow = lane >> 3;                  // 0..7
  const int scol = ((lane & 7) ^ srow) * 8;    // swizzled source column
  const int fk = (lane >> 4) * 8;
  const int fr = lane & 15;
  const int fx = fr & 7;
  const int mwr = (wave >> 2) * (MI * 16);     // wave row base
  const int nwr = (wave & 3) * 64;             // wave col base
  const int cA0 = (MI == 8) ? ((wave < 4) ? 2 * wave : 2 * wave + 8) : 2 * wave;
  const int cA1 = cA0 + 8;                     // MI=8 only
  const int cB0 = (wave >> 1) * 8 + 2 * (wave & 1);
  const int cB1 = cB0 + 4;
  const int kc0 = (((fk >> 3) ^ fx) << 3);
  const int kc1 = ((((32 + fk) >> 3) ^ fx) << 3);

  auto SA2 = [&](int p, int kt, int c) {
    stage16(srcA(c * 8 + srow, kt) + scol, &sm->a[p][c * 512]);
    stage16(srcA(c * 8 + 8 + srow, kt) + scol, &sm->a[p][(c + 1) * 512]);
  };
  auto SB2 = [&](int p, int kt, int c) {
    stage16(srcB(c * 8 + srow, kt) + scol, &sm->b[p][c * 512]);
    stage16(srcB(c * 8 + 8 + srow, kt) + scol, &sm->b[p][(c + 1) * 512]);
  };

  short8 af[4], bfv[4][2];
  auto LDB = [&](int p) {                      // MI4 path (both kks)
#pragma unroll
    for (int j = 0; j < 4; ++j) {
      bfv[j][0] = *(const short8*)&sm->b[p][(nwr + j * 16 + fr) * 64 + kc0];
      bfv[j][1] = *(const short8*)&sm->b[p][(nwr + j * 16 + fr) * 64 + kc1];
    }
  };
  auto LDBk = [&](int p, int kk, int kc) {     // MI8 path (one kk)
#pragma unroll
    for (int j = 0; j < 4; ++j)
      bfv[j][kk] = *(const short8*)&sm->b[p][(nwr + j * 16 + fr) * 64 + kc];
  };
  auto LDA4 = [&](int p, int iho, int kc) {
#pragma unroll
    for (int i = 0; i < 4; ++i)
      af[i] = *(const short8*)&sm->a[p][(mwr + iho + i * 16 + fr) * 64 + kc];
  };
  auto MMk = [&](int accb, int kk) {
#pragma unroll
    for (int i = 0; i < 4; ++i)
#pragma unroll
      for (int j = 0; j < 4; ++j)
        acc[accb + i][j] = __builtin_amdgcn_mfma_f32_16x16x32_bf16(
            af[i], bfv[j][kk], acc[accb + i][j], 0, 0, 0);
  };

  // prologue: tile 0 (A+B -> buf0) + B(1) -> buf1
  SA2(0, 0, cA0);
  if constexpr (MI == 8) SA2(0, 0, cA1);
  SB2(0, 0, cB0); SB2(0, 0, cB1);
  if (NK > 1) {
    SB2(1, 1, cB0); SB2(1, 1, cB1);
    asm volatile("s_waitcnt vmcnt(4)" ::: "memory");
  } else {
    asm volatile("s_waitcnt vmcnt(0)" ::: "memory");
  }
  SCB; __builtin_amdgcn_s_barrier(); SCB;

  for (int t = 0; t < NK; ++t) {
    const int p = t & 1, po = p ^ 1;
    const bool s1 = (t + 1 < NK), s2 = (t + 2 < NK);
    if constexpr (MI == 8) {
      // ---- PH1: (ih0,k0) ; stage A(t+1).h0 -> po ----
      LDBk(p, 0, kc0);
      LDA4(p, 0, kc0);
      if (s1) SA2(po, t + 1, cA0);
      SCB; __builtin_amdgcn_s_barrier(); LGKM0;
      __builtin_amdgcn_s_setprio(1); MMk(0, 0); __builtin_amdgcn_s_setprio(0);
      SCB; __builtin_amdgcn_s_barrier(); SCB;
      // ---- PH2: (ih0,k1) ; stage A(t+1).h1 -> po ----
      LDBk(p, 1, kc1);
      LDA4(p, 0, kc1);
      if (s1) SA2(po, t + 1, cA1);
      SCB; __builtin_amdgcn_s_barrier(); LGKM0;
      __builtin_amdgcn_s_setprio(1); MMk(0, 1); __builtin_amdgcn_s_setprio(0);
      SCB; __builtin_amdgcn_s_barrier(); SCB;
      // ---- PH3: (ih1,k0) ; stage B(t+2).h0 -> p (B(t) dead after PH2) ----
      LDA4(p, 64, kc0);
      if (s2) SB2(p, t + 2, cB0);
      SCB; __builtin_amdgcn_s_barrier(); LGKM0;
      __builtin_amdgcn_s_setprio(1); MMk(4, 0); __builtin_amdgcn_s_setprio(0);
      SCB; __builtin_amdgcn_s_barrier(); SCB;
      // ---- PH4: (ih1,k1) ; stage B(t+2).h1 ; counted wait ----
      LDA4(p, 64, kc1);
      if (s2) SB2(p, t + 2, cB1);
      SCB; __builtin_amdgcn_s_barrier(); LGKM0;
      __builtin_amdgcn_s_setprio(1); MMk(4, 1); __builtin_amdgcn_s_setprio(0);
      SCB;
      if (s2)      { asm volatile("s_waitcnt vmcnt(4)" ::: "memory"); }
      else if (s1) { asm volatile("s_waitcnt vmcnt(0)" ::: "memory"); }
      SCB; __builtin_amdgcn_s_barrier(); SCB;
    } else {
      // ---- MI4: round-8 proven path, unchanged ----
      if (s1) SA2(po, t + 1, cA0);
      LDB(p);
      LDA4(p, 0, kc0);
      LGKM0;
      __builtin_amdgcn_s_setprio(1); MMk(0, 0); __builtin_amdgcn_s_setprio(0);
      SCB; __builtin_amdgcn_s_barrier(); SCB;
      if (s2) { SB2(p, t + 2, cB0); SB2(p, t + 2, cB1); }
      LDA4(p, 0, kc1);
      LGKM0;
      __builtin_amdgcn_s_setprio(1); MMk(0, 1); __builtin_amdgcn_s_setprio(0);
      SCB;
      if (s2)      { asm volatile("s_waitcnt vmcnt(4)" ::: "memory"); }
      else if (s1) { asm volatile("s_waitcnt vmcnt(0)" ::: "memory"); }
      SCB; __builtin_amdgcn_s_barrier(); SCB;
    }
  }
}

// per-element epilogue: body(rr, cc, av) within the (MI*32) x 256 tile
template<int MI, typename F>
__device__ __forceinline__ void epiT(const f32x4 (&acc)[MI][4], F body) {
  const int lane = threadIdx.x & 63;
  const int wave = threadIdx.x >> 6;
  const int mwr = (wave >> 2) * (MI * 16), nwr = (wave & 3) * 64;
#pragma unroll
  for (int i = 0; i < MI; ++i)
#pragma unroll
    for (int j = 0; j < 4; ++j)
#pragma unroll
      for (int jj = 0; jj < 4; ++jj)
        body(mwr + i * 16 + ((lane >> 4) << 2) + jj,
             nwr + j * 16 + (lane & 15), acc[i][j][jj]);
}

// ---------------- prep kernels ----------------

__global__ void k_prep_x(const float* __restrict__ x, const float* __restrict__ wlr,
                         const float* __restrict__ wwd, unsigned short* __restrict__ xb,
                         float* __restrict__ lrlog, float* __restrict__ wdlog) {
  const int wave = threadIdx.x >> 6, lane = threadIdx.x & 63;
  const int row = blockIdx.x * 4 + wave;
  const float* xr = x + (size_t)row * DD;
  float s1 = 0.f, s2 = 0.f;
#pragma unroll
  for (int ch = 0; ch < 4; ++ch) {
    const int col = ch * 256 + lane * 4;
    float4 v = *(const float4*)(xr + col);
    float4 a = *(const float4*)(wlr + col);
    float4 b = *(const float4*)(wwd + col);
    s1 += v.x*a.x + v.y*a.y + v.z*a.z + v.w*a.w;
    s2 += v.x*b.x + v.y*b.y + v.z*b.z + v.w*b.w;
    uint2 u;
    u.x = (unsigned)f2bf(v.x) | ((unsigned)f2bf(v.y) << 16);
    u.y = (unsigned)f2bf(v.z) | ((unsigned)f2bf(v.w) << 16);
    *(uint2*)(xb + (size_t)row * DD + col) = u;
  }
#pragma unroll
  for (int off = 32; off > 0; off >>= 1) {
    s1 += __shfl_down(s1, off);
    s2 += __shfl_down(s2, off);
  }
  if (lane == 0) { lrlog[row] = s1; wdlog[row] = s2; }
}

__global__ void k_prep_w(const float* __restrict__ wq, const float* __restrict__ wk,
                         const float* __restrict__ wv, unsigned short* __restrict__ wqt,
                         unsigned short* __restrict__ wkt, unsigned short* __restrict__ wvtn,
                         unsigned short* __restrict__ wkr) {
  const int idx = blockIdx.x * 256 + threadIdx.x;
  if (blockIdx.z == 3) { wkr[idx] = f2bf(wk[idx]); return; }
  const int k = idx >> 10, n = idx & 1023;
  const float* src = (blockIdx.z == 0) ? wq : (blockIdx.z == 1) ? wk : wv;
  unsigned short* dst = (blockIdx.z == 0) ? wqt : (blockIdx.z == 1) ? wkt : wvtn;
  float v = src[(size_t)k * 1024 + n];
  if (blockIdx.z == 2) v = -v;
  dst[(size_t)n * 1024 + k] = f2bf(v);
}

__global__ void k_prep_h(const float* __restrict__ hid, unsigned short* __restrict__ wpb) {
  const size_t i = ((size_t)blockIdx.x * 256 + threadIdx.x) * 4;
  float4 v = *(const float4*)(hid + i);
  uint2 u;
  u.x = (unsigned)f2bf(v.x) | ((unsigned)f2bf(v.y) << 16);
  u.y = (unsigned)f2bf(v.z) | ((unsigned)f2bf(v.w) << 16);
  *(uint2*)(wpb + i) = u;
}

__global__ void k_bias2(const unsigned short* __restrict__ wpb, const float* __restrict__ bk,
                        const float* __restrict__ bv, float* __restrict__ bias2) {
  const int wave = threadIdx.x >> 6, lane = threadIdx.x & 63;
  const int row = blockIdx.x * 4 + wave;
  const unsigned short* wr = wpb + (size_t)row * HH;
  float s = 0.f;
#pragma unroll
  for (int ch = 0; ch < 4; ++ch) {
    const int col = ch * 256 + lane * 4;
    float4 a = *(const float4*)(bk + col);
    ushort4 u = *(const ushort4*)(wr + col);
    s += a.x * bf2f(u.x) + a.y * bf2f(u.y) + a.z * bf2f(u.z) + a.w * bf2f(u.w);
  }
#pragma unroll
  for (int off = 32; off > 0; off >>= 1) s += __shfl_down(s, off);
  if (lane == 0) bias2[row] = s - bv[row & 1023];
}

__global__ void k_scan(const float* __restrict__ lrlog, const float* __restrict__ wdlog,
                       const float* __restrict__ lbl, const float* __restrict__ blr,
                       const float* __restrict__ lbw, const float* __restrict__ bwd,
                       float* __restrict__ lr, float* __restrict__ c,
                       float* __restrict__ s, float* __restrict__ ecl) {
  const int b = blockIdx.x, t = threadIdx.x;
  __shared__ float sums[256];
  const float elr = expf(lbl[0]);
  const float ewd = expf(lbw[0]);
  const float blr0 = blr[0], bwd0 = bwd[0];
  float lw[8];
  const float* wb = wdlog + (size_t)b * LL + t * 8;
  float tot = 0.f;
#pragma unroll
  for (int i = 0; i < 8; ++i) {
    float z = wb[i] + bwd0;
    float sig = 1.f / (1.f + expf(-z));
    tot += log1pf(-ewd * sig);
    lw[i] = tot;
  }
  sums[t] = tot;
  __syncthreads();
  for (int off = 1; off < 256; off <<= 1) {
    float v = (t >= off) ? sums[t - off] : 0.f;
    __syncthreads();
    sums[t] += v;
    __syncthreads();
  }
  const float prev = (t > 0) ? sums[t - 1] : 0.f;
  const float ctot = sums[255];
  const float* lb = lrlog + (size_t)b * LL + t * 8;
#pragma unroll
  for (int i = 0; i < 8; ++i) {
    const int idx = b * LL + t * 8 + i;
    const float ci = prev + lw[i];
    c[idx] = ci;
    float zl = lb[i] + blr0;
    float lri = elr / (1.f + expf(-zl));
    lr[idx] = lri;
    s[idx] = lri * expf(ctot - ci);
  }
  if (t == 0) ecl[b] = expf(ctot);
}

// ---------------- GEMM kernels ----------------

// W2T[b][d][j] = sum_h Wp[b,d,h]*Wk[j,h] - Wv[j,d]  (MI=4, unchanged from r8)
__global__ __launch_bounds__(512, 2) void k11_gemm_m2(const unsigned short* __restrict__ wpb,
    const unsigned short* __restrict__ wkr, const unsigned short* __restrict__ wvtn,
    unsigned short* __restrict__ w2t) {
  __shared__ SmemT<4> sm;
  const int b = blockIdx.x;
  const int mt = blockIdx.y & 7, nt = blockIdx.y >> 3;
  const int m0 = mt * 128, n0 = nt * 256;
  f32x4 acc[4][4]; acc_initT<4>(acc);
  gemm11_core<4>(
    [&](int r, int kt) { return wpb + (size_t)b * DD * HH + (size_t)(m0 + r) * HH + kt * 64; },
    [&](int r, int kt) { return wkr + (size_t)(n0 + r) * HH + kt * 64; },
    HH / 64, &sm, acc);
  epiT<4>(acc, [&](int rr, int cc, float av) {
    const size_t gi = (size_t)(m0 + rr) * DD + (n0 + cc);
    w2t[(size_t)b * DD * DD + gi] = f2bf(av + bf2f(wvtn[gi]));   // wvtn = -Wv^T
  });
}

// Q = X*WqT + bq; q2 = exp(c[m]) * Q   (MI=8, new core)
__global__ __launch_bounds__(512, 2) void k11_gemm_q(const unsigned short* __restrict__ xb,
    const unsigned short* __restrict__ wt, const float* __restrict__ bias,
    const float* __restrict__ c, unsigned short* __restrict__ outb,
    unsigned short* __restrict__ q2b) {
  __shared__ SmemT<8> sm;
  const int mt = blockIdx.x * 8 + (blockIdx.y & 7);
  const int nt = blockIdx.y >> 3;
  const int m0 = mt * 256, n0 = nt * 256;
  f32x4 acc[8][4]; acc_initT<8>(acc);
  gemm11_core<8>(
    [&](int r, int kt) { return xb + (size_t)(m0 + r) * DD + kt * 64; },
    [&](int r, int kt) { return wt + (size_t)(n0 + r) * DD + kt * 64; },
    DD / 64, &sm, acc);
  const int lane = threadIdx.x & 63, wave = threadIdx.x >> 6;
  const int mwr = (wave >> 2) * 128, nwr = (wave & 3) * 64;
  float er[8][4];
#pragma unroll
  for (int i = 0; i < 8; ++i)
#pragma unroll
    for (int jj = 0; jj < 4; ++jj)
      er[i][jj] = __expf(c[m0 + mwr + i * 16 + ((lane >> 4) << 2) + jj]);
#pragma unroll
  for (int i = 0; i < 8; ++i)
#pragma unroll
    for (int j = 0; j < 4; ++j)
#pragma unroll
      for (int jj = 0; jj < 4; ++jj) {
        const int row = m0 + mwr + i * 16 + ((lane >> 4) << 2) + jj;
        const int col = n0 + nwr + j * 16 + (lane & 15);
        const float v = acc[i][j][jj] + bias[col];
        outb[(size_t)row * HH + col] = f2bf(v);
        q2b[(size_t)row * HH + col] = f2bf(v * er[i][jj]);
      }
}

__global__ __launch_bounds__(512, 2) void k11_gemm_k(const unsigned short* __restrict__ xb,
    const unsigned short* __restrict__ wt, const float* __restrict__ bias,
    const float* __restrict__ s, unsigned short* __restrict__ kb,
    unsigned short* __restrict__ k2t) {
  __shared__ SmemT<8> sm;
  const int mt = blockIdx.x * 8 + (blockIdx.y & 7);
  const int nt = blockIdx.y >> 3;
  const int m0 = mt * 256, n0 = nt * 256;
  f32x4 acc[8][4]; acc_initT<8>(acc);
  gemm11_core<8>(
    [&](int r, int kt) { return xb + (size_t)(m0 + r) * DD + kt * 64; },
    [&](int r, int kt) { return wt + (size_t)(n0 + r) * DD + kt * 64; },
    DD / 64, &sm, acc);
  const int lane = threadIdx.x & 63, wave = threadIdx.x >> 6;
  const int mwr = (wave >> 2) * 128, nwr = (wave & 3) * 64;
#pragma unroll
  for (int i = 0; i < 8; ++i)
#pragma unroll
    for (int j = 0; j < 4; ++j) {
      const int col = n0 + nwr + j * 16 + (lane & 15);
      const float bias_c = bias[col];
      const int row0 = m0 + mwr + i * 16 + ((lane >> 4) << 2);
      const int b = row0 >> 11, ml0 = row0 & 2047;
      unsigned short tmp[4];
#pragma unroll
      for (int jj = 0; jj < 4; ++jj) {
        float v = acc[i][j][jj] + bias_c;
        kb[(size_t)(row0 + jj) * HH + col] = f2bf(v);
        tmp[jj] = f2bf(v * s[row0 + jj]);
      }
      uint2 u;
      u.x = (unsigned)tmp[0] | ((unsigned)tmp[1] << 16);
      u.y = (unsigned)tmp[2] | ((unsigned)tmp[3] << 16);
      *(uint2*)&k2t[((size_t)b * HH + col) * LL + ml0] = u;
    }
}

// U = X*W2T + bias2, stored transposed ut[b][d][l]  (MI=8, new core)
__global__ __launch_bounds__(512, 2) void k11_gemm_u(const unsigned short* __restrict__ xb,
    const unsigned short* __restrict__ w2t, const float* __restrict__ bias2,
    unsigned short* __restrict__ ut) {
  __shared__ SmemT<8> sm;
  const int b = blockIdx.x;
  const int mt = blockIdx.x * 8 + (blockIdx.y & 7);
  const int nt = blockIdx.y >> 3;
  const int m0 = mt * 256, n0 = nt * 256;
  f32x4 acc[8][4]; acc_initT<8>(acc);
  gemm11_core<8>(
    [&](int r, int kt) { return xb + (size_t)(m0 + r) * DD + kt * 64; },
    [&](int r, int kt) { return w2t + (size_t)b * DD * DD + (size_t)(n0 + r) * DD + kt * 64; },
    DD / 64, &sm, acc);
  const int lane = threadIdx.x & 63, wave = threadIdx.x >> 6;
  const int mwr = (wave >> 2) * 128, nwr = (wave & 3) * 64;
#pragma unroll
  for (int i = 0; i < 8; ++i)
#pragma unroll
    for (int j = 0; j < 4; ++j) {
      const int col = n0 + nwr + j * 16 + (lane & 15);
      const float b2c = bias2[b * DD + col];
      const int row0 = m0 + mwr + i * 16 + ((lane >> 4) << 2);
      const int ml0 = row0 & 2047;
      unsigned short tmp[4];
#pragma unroll
      for (int jj = 0; jj < 4; ++jj) tmp[jj] = f2bf(acc[i][j][jj] + b2c);
      uint2 u;
      u.x = (unsigned)tmp[0] | ((unsigned)tmp[1] << 16);
      u.y = (unsigned)tmp[2] | ((unsigned)tmp[3] << 16);
      *(uint2*)&ut[((size_t)b * DD + col) * LL + ml0] = u;
    }
}

// pb[m,l] = -lr[l]*exp(c[m]-c[l]) * (Q K^T)[m,l] for l<=m, else 0.
// MI=4: 128x256 triangular tiles, 72/batch (unchanged from r8).
__global__ __launch_bounds__(512, 2) void k11_gemm_p(const unsigned short* __restrict__ qb,
    const unsigned short* __restrict__ kb, const float* __restrict__ lr,
    const float* __restrict__ c, unsigned short* __restrict__ pb) {
  __shared__ SmemT<4> sm;
  const int b = blockIdx.x;                    // XCD = batch (L2 locality)
  const int t = blockIdx.y;                    // 0..71
  int r = (int)((sqrtf(4.f * (float)t + 1.f) - 1.f) * 0.5f);
  while ((r + 1) * (r + 2) <= t) ++r;
  while (r * (r + 1) > t) --r;
  const int u = t - r * (r + 1);               // 0..2r+1
  const int mt = 2 * r + (u > r ? 1 : 0);
  const int nt2 = (u > r) ? (u - r - 1) : u;
  const int base = b * LL;
  const int m0 = mt * 128, n0 = nt2 * 256;
  f32x4 acc[4][4]; acc_initT<4>(acc);
  gemm11_core<4>(
    [&](int rr, int kt) { return qb + (size_t)(base + m0 + rr) * HH + kt * 64; },
    [&](int rr, int kt) { return kb + (size_t)(base + n0 + rr) * HH + kt * 64; },
    HH / 64, &sm, acc);
  epiT<4>(acc, [&](int rr, int cc, float av) {
    const int m = m0 + rr, l = n0 + cc;
    float v = 0.f;
    if (l <= m) v = -av * lr[base + l] * __expf(c[base + m] - c[base + l]);
    pb[((size_t)base + m) * LL + l] = f2bf(v);
  });
}

// y = pb*U + q2*Wp^T, fused K-sequence.  (MI=8, new core; grid (8,32),
// mt = y&7, nt = y>>3 -- same geometry whose v8-core baseline was 91.5us,
// so the delta attributes cleanly to the new schedule.)
__global__ __launch_bounds__(512, 2) void k11_gemm_y(const unsigned short* __restrict__ pb,
    const unsigned short* __restrict__ ut, const unsigned short* __restrict__ q2b,
    const unsigned short* __restrict__ wpb, float* __restrict__ out) {
  __shared__ SmemT<8> sm;
  const int b = blockIdx.x;
  const int mt = blockIdx.y & 7;
  const int nt = blockIdx.y >> 3;
  const int m0 = mt * 256, n0 = nt * 256;
  const int NK1 = (mt + 1) * 4;                 // pb cols l < (mt+1)*256
  f32x4 acc[8][4]; acc_initT<8>(acc);
  gemm11_core<8>(
    [&](int r, int kt) {
      return (kt < NK1) ? pb + (size_t)b * LL * LL + (size_t)(m0 + r) * LL + kt * 64
                        : q2b + ((size_t)b * LL + m0 + r) * HH + (kt - NK1) * 64;
    },
    [&](int r, int kt) {
      return (kt < NK1) ? ut + (size_t)b * DD * LL + (size_t)(n0 + r) * LL + kt * 64
                        : wpb + (size_t)b * DD * HH + (size_t)(n0 + r) * HH + (kt - NK1) * 64;
    },
    NK1 + 16, &sm, acc);
  epiT<8>(acc, [&](int rr, int cc, float av) {
    out[((size_t)b * LL + m0 + rr) * DD + (n0 + cc)] = av;
  });
}

// W_next = -Ut * K2t^T + ecl[b]*W_prev  (MI=4, unchanged from r8)
__global__ __launch_bounds__(512, 2) void k11_gemm_wn(const unsigned short* __restrict__ ut,
    const unsigned short* __restrict__ k2t, const float* __restrict__ hid,
    const float* __restrict__ ecl, float* __restrict__ out2) {
  __shared__ SmemT<4> sm;
  const int b = blockIdx.x;
  const int mt = blockIdx.y & 7, nt = blockIdx.y >> 3;
  const int m0 = mt * 128, n0 = nt * 256;
  f32x4 acc[4][4]; acc_initT<4>(acc);
  gemm11_core<4>(
    [&](int r, int kt) { return ut + (size_t)b * DD * LL + (size_t)(m0 + r) * LL + kt * 64; },
    [&](int r, int kt) { return k2t + (size_t)b * HH * LL + (size_t)(n0 + r) * LL + kt * 64; },
    LL / 64, &sm, acc);
  const float eclb = ecl[b];
  epiT<4>(acc, [&](int rr, int cc, float av) {
    const size_t gi = ((size_t)b * DD + (m0 + rr)) * HH + (n0 + cc);
    out2[gi] = -av + eclb * hid[gi];
  });
}

// ---------------- launcher ----------------

extern "C" void kernel_launch(void* const* d_in, const int* in_sizes, int n_in,
                              void* d_out, int out_size, void* d_ws, size_t ws_size,
                              hipStream_t stream) {
  (void)in_sizes; (void)n_in; (void)out_size; (void)ws_size;
  const float* x   = (const float*)d_in[0];
  const float* hid = (const float*)d_in[1];
  const float* lbl = (const float*)d_in[2];
  const float* wlr = (const float*)d_in[3];
  const float* blr = (const float*)d_in[4];
  const float* lbw = (const float*)d_in[5];
  const float* wwd = (const float*)d_in[6];
  const float* bwd = (const float*)d_in[7];
  const float* wq  = (const float*)d_in[8];
  const float* bq  = (const float*)d_in[9];
  const float* wk  = (const float*)d_in[10];
  const float* bk  = (const float*)d_in[11];
  const float* wv  = (const float*)d_in[12];
  const float* bv  = (const float*)d_in[13];
  float* out = (float*)d_out;

  char* w = (char*)d_ws;
  constexpr size_t SZ_XB  = (size_t)BL * DD * 2;
  constexpr size_t SZ_QB  = (size_t)BL * HH * 2;
  constexpr size_t SZ_KB  = (size_t)BL * HH * 2;
  constexpr size_t SZ_K2T = (size_t)BB * HH * LL * 2;
  constexpr size_t SZ_UT  = (size_t)BB * DD * LL * 2;
  constexpr size_t SZ_PB  = (size_t)BB * LL * LL * 2;
  constexpr size_t SZ_WT  = (size_t)DD * HH * 2;
  constexpr size_t SZ_WPB = (size_t)BB * DD * HH * 2;
  constexpr size_t SZ_V16 = (size_t)BL * 4;

  size_t off = 0;
  unsigned short* xb   = (unsigned short*)(w + off); off += SZ_XB;
  unsigned short* qb   = (unsigned short*)(w + off); off += SZ_QB;
  unsigned short* kb   = (unsigned short*)(w + off); off += SZ_KB;
  unsigned short* k2t  = (unsigned short*)(w + off); off += SZ_K2T;
  unsigned short* ut   = (unsigned short*)(w + off); off += SZ_UT;
  unsigned short* pb   = (unsigned short*)(w + off); off += SZ_PB;
  unsigned short* wqt  = (unsigned short*)(w + off); off += SZ_WT;
  unsigned short* wkt  = (unsigned short*)(w + off); off += SZ_WT;
  unsigned short* wvtn = (unsigned short*)(w + off); off += SZ_WT;
  unsigned short* wpb  = (unsigned short*)(w + off); off += SZ_WPB;
  float* lrlog = (float*)(w + off); off += SZ_V16;
  float* wdlog = (float*)(w + off); off += SZ_V16;
  float* lr    = (float*)(w + off); off += SZ_V16;
  float* c     = (float*)(w + off); off += SZ_V16;
  float* s     = (float*)(w + off); off += SZ_V16;
  float* ecl   = (float*)(w + off); off += 256;
  float* bias2 = (float*)(w + off); off += (size_t)BB * DD * 4;

  // w2t (16.8 MB) + wkr (2 MB) alias the pb region: dead before k11_gemm_p writes pb.
  unsigned short* w2t = pb;
  unsigned short* wkr = pb + (size_t)BB * DD * DD;

  // q2 scratch lives in d_out's W_next region; overwritten by k11_gemm_wn afterwards.
  unsigned short* q2b = (unsigned short*)(out + (size_t)BL * DD);
  float* out2 = out + (size_t)BL * DD;

  k_prep_x<<<dim3(BL / 4), 256, 0, stream>>>(x, wlr, wwd, xb, lrlog, wdlog);
  k_prep_w<<<dim3(4096, 1, 4), 256, 0, stream>>>(wq, wk, wv, wqt, wkt, wvtn, wkr);
  k_prep_h<<<dim3((unsigned)((size_t)BB * DD * HH / 1024)), 256, 0, stream>>>(hid, wpb);
  k_scan<<<dim3(BB), 256, 0, stream>>>(lrlog, wdlog, lbl, blr, lbw, bwd, lr, c, s, ecl);
  k_bias2<<<dim3(BB * DD / 4), 256, 0, stream>>>(wpb, bk, bv, bias2);

  k11_gemm_m2<<<dim3(8, 32), 512, 0, stream>>>(wpb, wkr, wvtn, w2t);
  k11_gemm_q<<<dim3(8, 32), 512, 0, stream>>>(xb, wqt, bq, c, qb, q2b);
  k11_gemm_k<<<dim3(8, 32), 512, 0, stream>>>(xb, wkt, bk, s, kb, k2t);
  k11_gemm_u<<<dim3(8, 32), 512, 0, stream>>>(xb, w2t, bias2, ut);
  k11_gemm_p<<<dim3(8, 72), 512, 0, stream>>>(qb, kb, lr, c, pb);
  k11_gemm_y<<<dim3(8, 32), 512, 0, stream>>>(pb, ut, q2b, wpb, out);
  k11_gemm_wn<<<dim3(8, 32), 512, 0, stream>>>(ut, k2t, hid, ecl, out2);
}